// Round 16
// baseline (543.673 us; speedup 1.0000x reference)
//
#include <hip/hip_runtime.h>
#include <math.h>

#define BB 64
#define TT 2048
#define ADIM 384
#define NE 10    // num_embeddings == LSTM hidden
#define NG 40    // 4*NE gates
#define HD 3     // hidden_dim (codebook width)

// ---------------- workspace layout (bytes) ----------------
#define OFF_X32   0ULL                        // BB*TT*NG*4 = 20971520 (+slack)
#define OFF_H     (41943040ULL + 126400ULL)   // BB*TT*NE*4 = 5242880
#define OFF_IDX   (OFF_H + 5242880ULL)        // BB*TT*4 = 524288
#define OFF_ACC   (OFF_IDX + 524288ULL)       // int64 fixed-point loss accum
#define OFF_CNT   (OFF_ACC + 8ULL)            // completion counter
#define OFF_DUMP  (OFF_ACC + 4096ULL)         // per-block dump (64 * 256B)

#define FIXSCALE  1099511627776.0             // 2^40

// ---------------- fast helpers ----------------
__device__ __forceinline__ float fexp2(float x) {   // HW 2^x, ~1 ulp
    float r;
    asm("v_exp_f32 %0, %1" : "=v"(r) : "v"(x));
    return r;
}
__device__ __forceinline__ float frcp(float d) {    // HW rcp, ~1 ulp
    float r;
    asm("v_rcp_f32 %0, %1" : "=v"(r) : "v"(d));
    return r;
}

template<int CTRL>
__device__ __forceinline__ float dpp_mov_f32(float x) {
    int v = __float_as_int(x);
    v = __builtin_amdgcn_update_dpp(v, v, CTRL, 0xF, 0xF, true);
    return __int_as_float(v);
}
template<int CTRL, int RMASK>
__device__ __forceinline__ float dpp_mov_f32m(float x) {
    int v = __float_as_int(x);
    v = __builtin_amdgcn_update_dpp(v, v, CTRL, RMASK, 0xF, true);
    return __int_as_float(v);
}

// ---------------- X = hs @ W_ih.T  (f32, dual accumulator; R12 exact) ------
// Block 0 thread 0 also zero-inits the loss accumulator + counter (stream
// order guarantees this lands before recur_tail reads them).
__global__ __launch_bounds__(256) void gemm_kernel(
        const float* __restrict__ hs, const float* __restrict__ W_ih,
        char* __restrict__ ws) {
    if (blockIdx.x == 0 && threadIdx.x == 0) {
        *(unsigned long long*)(ws + OFF_ACC) = 0ull;
        *(unsigned*)(ws + OFF_CNT) = 0u;
    }
    float* X32 = (float*)(ws + OFF_X32);
    int lane = threadIdx.x & 63;
    int wv = threadIdx.x >> 6;
    int cb = __builtin_amdgcn_readfirstlane(wv * 10);   // wave-uniform col base
    long row = (long)blockIdx.x * 64 + lane;            // < 131072
    const float* xr = hs + row * ADIM;
    float accA[10], accB[10];
#pragma unroll
    for (int j = 0; j < 10; ++j) { accA[j] = 0.0f; accB[j] = 0.0f; }
    for (int a0 = 0; a0 < ADIM; a0 += 4) {
        float4 xv = *(const float4*)(xr + a0);
#pragma unroll
        for (int j = 0; j < 10; ++j) {
            float4 wv4 = *(const float4*)(W_ih + (cb + j) * ADIM + a0);
            accA[j] = fmaf(wv4.x, xv.x, accA[j]);
            accA[j] = fmaf(wv4.y, xv.y, accA[j]);
            accB[j] = fmaf(wv4.z, xv.z, accB[j]);
            accB[j] = fmaf(wv4.w, xv.w, accB[j]);
        }
    }
    float* op = X32 + row * NG + cb;
#pragma unroll
    for (int j = 0; j < 10; ++j) op[j] = accA[j] + accB[j];
}

// ---------------- recur + inline tail: 64 blocks x 256 threads -------------
// Wave 0: in-register f64 setup + chain. Waves 1-3 park at __syncthreads.
// QUAD layout: lane 4m+j = gate j of embedding m; quad-redundant c,h
// REQUIRED by the DPP argmax reduce (R3/R11: keys must live in every mod-4
// congruence class). Argmax: f32 key with (15-m) packed in the low 4
// mantissa bits (2^-19 perturbation << observed >1e-5 margins), v_max_f32
// DPP reduce, s_idx straight from the winning key's low nibble — no ballot.
// 1 wave/SIMD (R8); all on VALU (R5); branchless per-lane stores (R8),
// dump lanes spread 4B apart (no same-address store serialization).
// Tail: all 256 threads; NLL partial -> int64 fixed-point atomic (exact,
// order-independent -> deterministic); last block writes the loss.
__global__ __launch_bounds__(256) void recur_tail_kernel(
        const float* __restrict__ W_ih, const float* __restrict__ codebook,
        const float* __restrict__ qs_W, const float* __restrict__ qs_b,
        const float* __restrict__ b_ih, const float* __restrict__ b_hh,
        const float* __restrict__ W_hh, const int* __restrict__ inds,
        float* __restrict__ out_embs, char* __restrict__ ws) {
    __shared__ double red[256];
    const int b = blockIdx.x;
    const int tid = threadIdx.x;

    if (tid < 64) {
        const int k = tid;
        const int j = k & 3;
        const int m = k >> 2;
        const bool valid = (k < NG);
        const int col = valid ? (j * 10 + m) : (NG - 1);
        const bool isg = (j == 2);

        // per-lane f64 setup (identical numerics to R12's setup_kernel)
        double M0 = 0, M1 = 0, M2 = 0, qbd = 0;
        for (int a = 0; a < ADIM; ++a) {
            double w = (double)W_ih[col * ADIM + a];
            M0 = fma(w, (double)qs_W[a * HD + 0], M0);
            M1 = fma(w, (double)qs_W[a * HD + 1], M1);
            M2 = fma(w, (double)qs_W[a * HD + 2], M2);
            qbd = fma(w, (double)qs_b[a], qbd);
        }
        double biasd = (double)b_ih[col] + (double)b_hh[col];
        float etab[NE];
#pragma unroll
        for (int i = 0; i < NE; ++i) {
            double e = biasd + qbd;          // t>0 esel includes bias + qb
            e = fma((double)codebook[i * HD + 0], M0, e);
            e = fma((double)codebook[i * HD + 1], M1, e);
            e = fma((double)codebook[i * HD + 2], M2, e);
            etab[i] = (float)e;
        }
        float esel = (float)biasd;           // t==0: gate = x + bias (no qs)

        const float LOG2E = 1.44269504088896340736f;
        const float Lg   = isg ? (-2.0f * LOG2E) : (-LOG2E);
        const float amul = isg ? 2.0f : 1.0f;
        const float aadd = isg ? -1.0f : 0.0f;
        const float L2   = -2.0f * LOG2E;

        float whh[NE];
#pragma unroll
        for (int mm = 0; mm < NE; ++mm) whh[mm] = W_hh[col * NE + mm];

        const float* Xb = (const float*)(ws + OFF_X32) + (long)b * TT * NG;

        const bool is_h = ((k & 3) == 0) && valid;
        const bool is_i = (k == NG);
        unsigned voff = is_h ? (unsigned)(OFF_H + ((unsigned)b * TT * NE + m) * 4u)
                      : is_i ? (unsigned)(OFF_IDX + (unsigned)b * TT * 4u)
                             : (unsigned)(OFF_DUMP + (unsigned)b * 256u + (unsigned)k * 4u);
        const unsigned vstep = is_h ? (unsigned)(NE * 4) : is_i ? 4u : 0u;

        // argmax key masks: valid -> (hI & ~15) | (15-m); invalid -> -inf
        const unsigned kAnd = valid ? 0xFFFFFFF0u : 0u;
        const unsigned kOr  = valid ? (unsigned)(15 - m) : 0xFF800000u;

        // prefetch ring depth 4 (overrun reads stay inside allocated ws slack)
        float xs0 = Xb[0 * NG + col];
        float xs1 = Xb[1 * NG + col];
        float xs2 = Xb[2 * NG + col];
        float xs3 = Xb[3 * NG + col];

        float ha[NE];
#pragma unroll
        for (int mm = 0; mm < NE; ++mm) ha[mm] = 0.0f;
        float c = 0.0f;

        auto step = [&](float& xslot, int t) {
            float xg = xslot;
            xslot = Xb[(t + 4) * NG + col];

            float p0 = fmaf(ha[1], whh[1], ha[0] * whh[0]);
            float p1 = fmaf(ha[3], whh[3], ha[2] * whh[2]);
            float p2 = fmaf(ha[5], whh[5], ha[4] * whh[4]);
            float p3 = fmaf(ha[7], whh[7], ha[6] * whh[6]);
            float p4 = fmaf(ha[9], whh[9], ha[8] * whh[8]);
            float dotE = ((p0 + p1) + (p2 + p3)) + (p4 + esel);
            float g32 = xg + dotE;

            float e1 = fexp2(g32 * Lg);
            float r1 = frcp(1.0f + e1);
            float act = fmaf(amul, r1, aadd);

            // quad-redundant c,h REQUIRED by the argmax reduce (R3/R11 bug)
            float fiv = dpp_mov_f32<0x00>(act);
            float ffv = dpp_mov_f32<0x55>(act);
            float fgv = dpp_mov_f32<0xAA>(act);
            float fov = dpp_mov_f32<0xFF>(act);
            c = fmaf(ffv, c, fiv * fgv);

            float e2 = fexp2(fabsf(c) * L2);
            float r2 = frcp(1.0f + e2);
            float th = fmaf(2.0f, r2, -1.0f);
            float h = __builtin_copysignf(fov * th, c);   // v_bfi
            int hI = __float_as_int(h);

            // argmax: f32 key, index in low nibble, v_max_f32 DPP reduce
            float key = __int_as_float((int)(((unsigned)hI & kAnd) | kOr));
            key = fmaxf(key, dpp_mov_f32m<0x124, 0xF>(key));  // row_ror:4
            key = fmaxf(key, dpp_mov_f32m<0x128, 0xF>(key));  // row_ror:8
            key = fmaxf(key, dpp_mov_f32m<0x142, 0xA>(key));  // bcast15
            key = fmaxf(key, dpp_mov_f32m<0x143, 0xC>(key));  // bcast31
            int slo = __builtin_amdgcn_readlane(__float_as_int(key), 32);
            int s_idx = 15 - (slo & 15);     // wave-uniform argmax index

            // branchless store: all 64 lanes store 4B (h / idx / dump)
            int val = is_h ? hI : s_idx;
            *(int*)(ws + voff) = val;
            voff += vstep;

            // broadcast h into SGPR-resident ha[] (quad-lane 4m per embedding)
#pragma unroll
            for (int mm = 0; mm < NE; ++mm)
                ha[mm] = __int_as_float(__builtin_amdgcn_readlane(hI, 4 * mm));

            // esel = etab[s_idx] (includes bias+qb): 4-level bit-tree on VALU
            float a0 = (s_idx & 1) ? etab[1] : etab[0];
            float a1 = (s_idx & 1) ? etab[3] : etab[2];
            float a2 = (s_idx & 1) ? etab[5] : etab[4];
            float a3 = (s_idx & 1) ? etab[7] : etab[6];
            float a4 = (s_idx & 1) ? etab[9] : etab[8];
            float b0 = (s_idx & 2) ? a1 : a0;
            float b1 = (s_idx & 2) ? a3 : a2;
            float c0 = (s_idx & 4) ? b1 : b0;
            esel = (s_idx & 8) ? a4 : c0;
        };

        for (int t = 0; t < TT; t += 4) {
            step(xs0, t);
            step(xs1, t + 1);
            step(xs2, t + 2);
            step(xs3, t + 3);
        }
    }

    __syncthreads();   // waves 1-3 parked here during the chain (no issue)

    // ---------------- inline tail for batch b (all 256 threads) ------------
    const float* h_ws = (const float*)(ws + OFF_H);
    const int* idx_ws = (const int*)(ws + OFF_IDX);
    double psum = 0.0;
    for (int t = tid; t < TT; t += 256) {
        long i = (long)b * TT + t;
        int idx = idx_ws[i];
        out_embs[i * 3 + 0] = codebook[idx * 3 + 0];
        out_embs[i * 3 + 1] = codebook[idx * 3 + 1];
        out_embs[i * 3 + 2] = codebook[idx * 3 + 2];

        const float* hp = h_ws + i * NE;
        double hv[NE];
#pragma unroll
        for (int mm = 0; mm < NE; ++mm) hv[mm] = (double)hp[mm];
        double mx = hv[0];
#pragma unroll
        for (int mm = 1; mm < NE; ++mm) mx = fmax(mx, hv[mm]);
        double sdn = 0.0;
#pragma unroll
        for (int mm = 0; mm < NE; ++mm) sdn += exp(hv[mm] - mx);
        int ind = inds[i];
        psum += (double)hp[ind] - (mx + log(sdn));
    }
    red[tid] = psum;
    __syncthreads();
    for (int st = 128; st > 0; st >>= 1) {
        if (tid < st) red[tid] += red[tid + st];
        __syncthreads();
    }
    if (tid == 0) {
        // int64 fixed-point accumulate: order-independent -> deterministic
        long long contrib = (long long)llrint(red[0] * FIXSCALE);
        atomicAdd((unsigned long long*)(ws + OFF_ACC),
                  (unsigned long long)contrib);
        __threadfence();
        unsigned old = atomicAdd((unsigned*)(ws + OFF_CNT), 1u);
        if (old == BB - 1) {                 // last block finishes the loss
            __threadfence();
            long long tot = (long long)__hip_atomic_load(
                (unsigned long long*)(ws + OFF_ACC),
                __ATOMIC_ACQUIRE, __HIP_MEMORY_SCOPE_AGENT);
            double s = (double)tot * (1.0 / FIXSCALE);
            out_embs[(size_t)BB * TT * HD] =
                (float)(-s / (double)(BB * TT));
        }
    }
}

extern "C" void kernel_launch(void* const* d_in, const int* in_sizes, int n_in,
                              void* d_out, int out_size, void* d_ws, size_t ws_size,
                              hipStream_t stream) {
    const float* hs       = (const float*)d_in[0];
    const int*   inds     = (const int*)d_in[1];
    const float* codebook = (const float*)d_in[2];
    const float* W_ih     = (const float*)d_in[3];
    const float* W_hh     = (const float*)d_in[4];
    const float* b_ih     = (const float*)d_in[5];
    const float* b_hh     = (const float*)d_in[6];
    const float* qs_W     = (const float*)d_in[7];
    const float* qs_b     = (const float*)d_in[8];
    float* out = (float*)d_out;

    char* ws = (char*)d_ws;

    gemm_kernel<<<2048, 256, 0, stream>>>(hs, W_ih, ws);
    recur_tail_kernel<<<BB, 256, 0, stream>>>(W_ih, codebook, qs_W, qs_b,
                                              b_ih, b_hh, W_hh, inds, out, ws);
}

// Round 17
// 536.877 us; speedup vs baseline: 1.0127x; 1.0127x over previous
//
#include <hip/hip_runtime.h>
#include <math.h>

#define BB 64
#define TT 2048
#define ADIM 384
#define NE 10    // num_embeddings == LSTM hidden
#define NG 40    // 4*NE gates
#define HD 3     // hidden_dim (codebook width)

// ---------------- workspace layout (bytes) ----------------
#define OFF_X32   0ULL                        // BB*TT*NG*4 = 20971520 (+slack)
#define OFF_H     (41943040ULL + 126400ULL)   // BB*TT*NE*4 = 5242880
#define OFF_IDX   (OFF_H + 5242880ULL)        // BB*TT*4 = 524288
#define OFF_ACC   (OFF_IDX + 524288ULL)       // int64 fixed-point loss accum
#define OFF_CNT   (OFF_ACC + 8ULL)            // completion counter
#define OFF_DUMP  (OFF_ACC + 4096ULL)         // per-block dump (64 * 256B)

#define FIXSCALE  1099511627776.0             // 2^40

// ---------------- fast helpers ----------------
__device__ __forceinline__ float fexp2(float x) {   // HW 2^x, ~1 ulp
    float r;
    asm("v_exp_f32 %0, %1" : "=v"(r) : "v"(x));
    return r;
}
__device__ __forceinline__ float frcp(float d) {    // HW rcp, ~1 ulp
    float r;
    asm("v_rcp_f32 %0, %1" : "=v"(r) : "v"(d));
    return r;
}

template<int CTRL>
__device__ __forceinline__ float dpp_mov_f32(float x) {
    int v = __float_as_int(x);
    v = __builtin_amdgcn_update_dpp(v, v, CTRL, 0xF, 0xF, true);
    return __int_as_float(v);
}
template<int CTRL, int RMASK>
__device__ __forceinline__ unsigned dpp_mov_u32(unsigned x) {
    int v = __builtin_amdgcn_update_dpp((int)x, (int)x, CTRL, RMASK, 0xF, true);
    return (unsigned)v;
}
__device__ __forceinline__ unsigned umax2(unsigned a, unsigned b) {
    return a > b ? a : b;
}

// ---------------- X = hs @ W_ih.T  (f32, dual accumulator; R12 exact) ------
// Block 0 thread 0 also zero-inits the loss accumulator + counter (stream
// order guarantees this lands before recur_tail reads them).
__global__ __launch_bounds__(256) void gemm_kernel(
        const float* __restrict__ hs, const float* __restrict__ W_ih,
        char* __restrict__ ws) {
    if (blockIdx.x == 0 && threadIdx.x == 0) {
        *(unsigned long long*)(ws + OFF_ACC) = 0ull;
        *(unsigned*)(ws + OFF_CNT) = 0u;
    }
    float* X32 = (float*)(ws + OFF_X32);
    int lane = threadIdx.x & 63;
    int wv = threadIdx.x >> 6;
    int cb = __builtin_amdgcn_readfirstlane(wv * 10);   // wave-uniform col base
    long row = (long)blockIdx.x * 64 + lane;            // < 131072
    const float* xr = hs + row * ADIM;
    float accA[10], accB[10];
#pragma unroll
    for (int j = 0; j < 10; ++j) { accA[j] = 0.0f; accB[j] = 0.0f; }
    for (int a0 = 0; a0 < ADIM; a0 += 4) {
        float4 xv = *(const float4*)(xr + a0);
#pragma unroll
        for (int j = 0; j < 10; ++j) {
            float4 wv4 = *(const float4*)(W_ih + (cb + j) * ADIM + a0);
            accA[j] = fmaf(wv4.x, xv.x, accA[j]);
            accA[j] = fmaf(wv4.y, xv.y, accA[j]);
            accB[j] = fmaf(wv4.z, xv.z, accB[j]);
            accB[j] = fmaf(wv4.w, xv.w, accB[j]);
        }
    }
    float* op = X32 + row * NG + cb;
#pragma unroll
    for (int j = 0; j < 10; ++j) op[j] = accA[j] + accB[j];
}

// ---------------- recur + inline tail: 64 blocks x 256 threads -------------
// Wave 0: in-register f64 setup + R15 chain (measured-fastest variant:
// sortable-u32 keys + ballot first-index argmax). Waves 1-3 park at
// __syncthreads (no issue traffic). QUAD layout: lane 4m+j = gate j of
// embedding m; quad-redundant c,h REQUIRED by the DPP argmax reduce
// (R3/R11: keys must live in every mod-4 congruence class). 1 wave/SIMD
// (R8); all on VALU (R5); branchless stores, dump lanes spread 4B (R16).
// Tail: all 256 threads; NLL partial -> int64 fixed-point atomic (exact,
// order-independent -> deterministic); last block writes the loss (R16).
__global__ __launch_bounds__(256) void recur_tail_kernel(
        const float* __restrict__ W_ih, const float* __restrict__ codebook,
        const float* __restrict__ qs_W, const float* __restrict__ qs_b,
        const float* __restrict__ b_ih, const float* __restrict__ b_hh,
        const float* __restrict__ W_hh, const int* __restrict__ inds,
        float* __restrict__ out_embs, char* __restrict__ ws) {
    __shared__ double red[256];
    const int b = blockIdx.x;
    const int tid = threadIdx.x;

    if (tid < 64) {
        const int k = tid;
        const int j = k & 3;
        const int m = k >> 2;
        const bool valid = (k < NG);
        const int col = valid ? (j * 10 + m) : (NG - 1);
        const bool isg = (j == 2);

        // per-lane f64 setup (identical numerics to R12's setup_kernel)
        double M0 = 0, M1 = 0, M2 = 0, qbd = 0;
        for (int a = 0; a < ADIM; ++a) {
            double w = (double)W_ih[col * ADIM + a];
            M0 = fma(w, (double)qs_W[a * HD + 0], M0);
            M1 = fma(w, (double)qs_W[a * HD + 1], M1);
            M2 = fma(w, (double)qs_W[a * HD + 2], M2);
            qbd = fma(w, (double)qs_b[a], qbd);
        }
        double biasd = (double)b_ih[col] + (double)b_hh[col];
        float etab[NE];
#pragma unroll
        for (int i = 0; i < NE; ++i) {
            double e = biasd + qbd;          // t>0 esel includes bias + qb
            e = fma((double)codebook[i * HD + 0], M0, e);
            e = fma((double)codebook[i * HD + 1], M1, e);
            e = fma((double)codebook[i * HD + 2], M2, e);
            etab[i] = (float)e;
        }
        float esel = (float)biasd;           // t==0: gate = x + bias (no qs)

        const float LOG2E = 1.44269504088896340736f;
        const float Lg   = isg ? (-2.0f * LOG2E) : (-LOG2E);
        const float amul = isg ? 2.0f : 1.0f;
        const float aadd = isg ? -1.0f : 0.0f;
        const float L2   = -2.0f * LOG2E;

        float whh[NE];
#pragma unroll
        for (int mm = 0; mm < NE; ++mm) whh[mm] = W_hh[col * NE + mm];

        const float* Xb = (const float*)(ws + OFF_X32) + (long)b * TT * NG;

        const bool is_h = ((k & 3) == 0) && valid;
        const bool is_i = (k == NG);
        unsigned voff = is_h ? (unsigned)(OFF_H + ((unsigned)b * TT * NE + m) * 4u)
                      : is_i ? (unsigned)(OFF_IDX + (unsigned)b * TT * 4u)
                             : (unsigned)(OFF_DUMP + (unsigned)b * 256u + (unsigned)k * 4u);
        const unsigned vstep = is_h ? (unsigned)(NE * 4) : is_i ? 4u : 0u;
        const unsigned vmask = valid ? 0xFFFFFFFFu : 0u;   // keys on ALL 40 lanes

        // prefetch ring depth 4 (overrun reads stay inside allocated ws slack)
        float xs0 = Xb[0 * NG + col];
        float xs1 = Xb[1 * NG + col];
        float xs2 = Xb[2 * NG + col];
        float xs3 = Xb[3 * NG + col];

        float ha[NE];
#pragma unroll
        for (int mm = 0; mm < NE; ++mm) ha[mm] = 0.0f;
        float c = 0.0f;

        auto step = [&](float& xslot, int t) {
            float xg = xslot;
            xslot = Xb[(t + 4) * NG + col];

            float p0 = fmaf(ha[1], whh[1], ha[0] * whh[0]);
            float p1 = fmaf(ha[3], whh[3], ha[2] * whh[2]);
            float p2 = fmaf(ha[5], whh[5], ha[4] * whh[4]);
            float p3 = fmaf(ha[7], whh[7], ha[6] * whh[6]);
            float p4 = fmaf(ha[9], whh[9], ha[8] * whh[8]);
            float dotE = ((p0 + p1) + (p2 + p3)) + (p4 + esel);
            float g32 = xg + dotE;

            float e1 = fexp2(g32 * Lg);
            float r1 = frcp(1.0f + e1);
            float act = fmaf(amul, r1, aadd);

            // quad-redundant c,h REQUIRED by the argmax reduce (R3/R11 bug)
            float fiv = dpp_mov_f32<0x00>(act);
            float ffv = dpp_mov_f32<0x55>(act);
            float fgv = dpp_mov_f32<0xAA>(act);
            float fov = dpp_mov_f32<0xFF>(act);
            c = fmaf(ffv, c, fiv * fgv);

            float e2 = fexp2(fabsf(c) * L2);
            float r2 = frcp(1.0f + e2);
            float th = fmaf(2.0f, r2, -1.0f);
            float habs = fov * th;
            int hI = __float_as_int(habs) | (__float_as_int(c) & 0x80000000);

            // EXACT argmax: sortable-u32 key, DPP u32 max, ballot+ctz ties
            int smsk = hI >> 31;
            unsigned key0 = ((unsigned)(hI ^ (smsk | (int)0x80000000))) & vmask;
            unsigned kr = umax2(key0, dpp_mov_u32<0x124, 0xF>(key0));  // ror:4
            kr = umax2(kr, dpp_mov_u32<0x128, 0xF>(kr));               // ror:8
            kr = umax2(kr, dpp_mov_u32<0x142, 0xA>(kr));               // bcast15
            kr = umax2(kr, dpp_mov_u32<0x143, 0xC>(kr));               // bcast31
            unsigned sMax = (unsigned)__builtin_amdgcn_readlane((int)kr, 32);
            unsigned long long ball = __ballot(key0 == sMax);
            int s_idx = ((int)__builtin_ctzll(ball)) >> 2;   // lowest m

            // branchless store: all 64 lanes store 4B (h / idx / dump)
            int val = is_h ? hI : s_idx;
            *(int*)(ws + voff) = val;
            voff += vstep;

            // broadcast h into SGPR-resident ha[] (quad-lane 4m per embedding)
#pragma unroll
            for (int mm = 0; mm < NE; ++mm)
                ha[mm] = __int_as_float(__builtin_amdgcn_readlane(hI, 4 * mm));

            // esel = etab[s_idx] (includes bias+qb): 4-level bit-tree on VALU
            float a0 = (s_idx & 1) ? etab[1] : etab[0];
            float a1 = (s_idx & 1) ? etab[3] : etab[2];
            float a2 = (s_idx & 1) ? etab[5] : etab[4];
            float a3 = (s_idx & 1) ? etab[7] : etab[6];
            float a4 = (s_idx & 1) ? etab[9] : etab[8];
            float b0 = (s_idx & 2) ? a1 : a0;
            float b1 = (s_idx & 2) ? a3 : a2;
            float c0 = (s_idx & 4) ? b1 : b0;
            esel = (s_idx & 8) ? a4 : c0;
        };

        for (int t = 0; t < TT; t += 4) {
            step(xs0, t);
            step(xs1, t + 1);
            step(xs2, t + 2);
            step(xs3, t + 3);
        }
    }

    __syncthreads();   // waves 1-3 parked here during the chain (no issue)

    // ---------------- inline tail for batch b (all 256 threads) ------------
    const float* h_ws = (const float*)(ws + OFF_H);
    const int* idx_ws = (const int*)(ws + OFF_IDX);
    double psum = 0.0;
    for (int t = tid; t < TT; t += 256) {
        long i = (long)b * TT + t;
        int idx = idx_ws[i];
        out_embs[i * 3 + 0] = codebook[idx * 3 + 0];
        out_embs[i * 3 + 1] = codebook[idx * 3 + 1];
        out_embs[i * 3 + 2] = codebook[idx * 3 + 2];

        const float* hp = h_ws + i * NE;
        double hv[NE];
#pragma unroll
        for (int mm = 0; mm < NE; ++mm) hv[mm] = (double)hp[mm];
        double mx = hv[0];
#pragma unroll
        for (int mm = 1; mm < NE; ++mm) mx = fmax(mx, hv[mm]);
        double sdn = 0.0;
#pragma unroll
        for (int mm = 0; mm < NE; ++mm) sdn += exp(hv[mm] - mx);
        int ind = inds[i];
        psum += (double)hp[ind] - (mx + log(sdn));
    }
    red[tid] = psum;
    __syncthreads();
    for (int st = 128; st > 0; st >>= 1) {
        if (tid < st) red[tid] += red[tid + st];
        __syncthreads();
    }
    if (tid == 0) {
        // int64 fixed-point accumulate: order-independent -> deterministic
        long long contrib = (long long)llrint(red[0] * FIXSCALE);
        atomicAdd((unsigned long long*)(ws + OFF_ACC),
                  (unsigned long long)contrib);
        __threadfence();
        unsigned old = atomicAdd((unsigned*)(ws + OFF_CNT), 1u);
        if (old == BB - 1) {                 // last block finishes the loss
            __threadfence();
            long long tot = (long long)__hip_atomic_load(
                (unsigned long long*)(ws + OFF_ACC),
                __ATOMIC_ACQUIRE, __HIP_MEMORY_SCOPE_AGENT);
            double s = (double)tot * (1.0 / FIXSCALE);
            out_embs[(size_t)BB * TT * HD] =
                (float)(-s / (double)(BB * TT));
        }
    }
}

extern "C" void kernel_launch(void* const* d_in, const int* in_sizes, int n_in,
                              void* d_out, int out_size, void* d_ws, size_t ws_size,
                              hipStream_t stream) {
    const float* hs       = (const float*)d_in[0];
    const int*   inds     = (const int*)d_in[1];
    const float* codebook = (const float*)d_in[2];
    const float* W_ih     = (const float*)d_in[3];
    const float* W_hh     = (const float*)d_in[4];
    const float* b_ih     = (const float*)d_in[5];
    const float* b_hh     = (const float*)d_in[6];
    const float* qs_W     = (const float*)d_in[7];
    const float* qs_b     = (const float*)d_in[8];
    float* out = (float*)d_out;

    char* ws = (char*)d_ws;

    gemm_kernel<<<2048, 256, 0, stream>>>(hs, W_ih, ws);
    recur_tail_kernel<<<BB, 256, 0, stream>>>(W_ih, codebook, qs_W, qs_b,
                                              b_ih, b_hh, W_hh, inds, out, ws);
}